// Round 7
// baseline (235.675 us; speedup 1.0000x reference)
//
#include <hip/hip_runtime.h>

// ---- problem geometry ----
#define D_MODEL 512
#define HD      1960
#define NPAD    2048          // HD padded to tile multiple
#define NVECS   720
#define MROWS   14400         // 4*3600
#define MPAD    14592         // 57*256
#define HP      66
#define WP      114
#define IMGPIX  7524          // HP*WP

typedef __bf16 bf16x8 __attribute__((ext_vector_type(8)));
typedef float  f32x4  __attribute__((ext_vector_type(4)));

__device__ __forceinline__ unsigned short f2bf(float f) {
    unsigned u = __builtin_bit_cast(unsigned, f);
    u += 0x7FFFu + ((u >> 16) & 1u);   // RNE
    return (unsigned short)(u >> 16);
}
__device__ __forceinline__ float bf2f(unsigned short s) {
    unsigned u = ((unsigned)s) << 16;
    return __builtin_bit_cast(float, u);
}

__device__ __forceinline__ void gload_lds16(const unsigned short* g, unsigned short* l) {
    __builtin_amdgcn_global_load_lds(
        (const __attribute__((address_space(1))) unsigned int*)g,
        (__attribute__((address_space(3))) unsigned int*)l,
        16, 0, 0);
}

// ---- convert x (fp32) -> bf16, zero-pad rows [14400,14592) ----
__global__ void cvt_x(const float* __restrict__ x, unsigned short* __restrict__ xb) {
    size_t i = ((size_t)blockIdx.x * 256 + threadIdx.x) * 4;
    const size_t valid = (size_t)MROWS * D_MODEL;
    if (i >= (size_t)MPAD * D_MODEL) return;
    ushort4 o;
    if (i < valid) {
        float4 v = *(const float4*)(x + i);
        o.x = f2bf(v.x); o.y = f2bf(v.y); o.z = f2bf(v.z); o.w = f2bf(v.w);
    } else {
        o.x = o.y = o.z = o.w = 0;
    }
    *(ushort4*)(xb + i) = o;
}

// ---- tiled transpose + fp32->bf16, zero-fill outside src ----
__global__ void transpose_cvt(const float* __restrict__ src, unsigned short* __restrict__ dst,
                              int srcR, int srcC, int dstR, int dstC) {
    __shared__ float tile[32][33];
    int c0 = blockIdx.x * 32;
    int r0 = blockIdx.y * 32;
    int tx = threadIdx.x, ty = threadIdx.y;   // (32,8)
    #pragma unroll
    for (int i = 0; i < 32; i += 8) {
        int sr = c0 + ty + i, sc = r0 + tx;
        tile[ty + i][tx] = (sr < srcR && sc < srcC) ? src[(size_t)sr * srcC + sc] : 0.f;
    }
    __syncthreads();
    #pragma unroll
    for (int i = 0; i < 32; i += 8) {
        int dr = r0 + ty + i, dc = c0 + tx;
        if (dr < dstR && dc < dstC)
            dst[(size_t)dr * dstC + dc] = f2bf(tile[tx][ty + i]);
    }
}

// ---- 256x256 BK=32 2-phase bf16 GEMM: C = A(MxK) * BT(NxK)^T (+bias) ----
// 8 waves (2 wr x 4 wc), wave tile 128x64. LDS 64KB (2 bufs x [A 16KB | B 16KB]).
// LDS layout per matrix tile: paired rows. phys (row'=row>>1, slot 0..7), 128B rows.
//   phys slot sp at row' holds logical (rp,kq) with (rp*4+kq) = sp ^ (row'&7),
//   data = element rows row'*2+rp, k-cols kq*8..kq*8+7.  (involution; conflict-free reads)
// MODE 0: out bf16 TRANSPOSED  hT[col*MPAD + row], skip cols >= validN (GEMM1)
// MODE 1: out fp32 row-major ldc=512, skip rows >= validM            (GEMM2)
template<int MODE>
__global__ __launch_bounds__(512, 2) void gemm_bt2(const unsigned short* __restrict__ A,
                        const unsigned short* __restrict__ BT,
                        const float* __restrict__ bias,
                        void* __restrict__ Cout,
                        int K, int validN, int validM) {
    __shared__ unsigned short lds[2][16384];   // 2 x 32KB
    const int t    = threadIdx.x;
    const int lane = t & 63;
    const int wid  = t >> 6;
    const int wr   = wid >> 2, wc = wid & 3;
    const int lr   = lane & 15, lh = lane >> 4;
    const int m0   = blockIdx.y * 256, n0 = blockIdx.x * 256;

    // staging: thread handles chunks t and t+512 (16B each) of both A and B tiles
    const int ci0 = t, ci1 = t + 512;
    const int r0 = ci0 >> 3, v0 = (ci0 & 7) ^ (r0 & 7);
    const int r1 = ci1 >> 3, v1 = (ci1 & 7) ^ (r1 & 7);
    const size_t sA0 = (size_t)(m0 + r0 * 2 + (v0 >> 2)) * K + ((v0 & 3) << 3);
    const size_t sA1 = (size_t)(m0 + r1 * 2 + (v1 >> 2)) * K + ((v1 & 3) << 3);
    const size_t sB0 = (size_t)(n0 + r0 * 2 + (v0 >> 2)) * K + ((v0 & 3) << 3);
    const size_t sB1 = (size_t)(n0 + r1 * 2 + (v1 >> 2)) * K + ((v1 & 3) << 3);

    // ds_read physical slot (per-thread constant) and row' sub-index
    const int sl  = (((lane & 1) << 2) | lh) ^ ((lane >> 1) & 7);
    const int rh  = (lane & 15) >> 1;

#define STAGE(buf, kt) do { \
        unsigned short* lb = &lds[buf][0]; \
        gload_lds16(A  + sA0 + (kt), lb + t * 8); \
        gload_lds16(A  + sA1 + (kt), lb + (t + 512) * 8); \
        gload_lds16(BT + sB0 + (kt), lb + 8192 + t * 8); \
        gload_lds16(BT + sB1 + (kt), lb + 8192 + (t + 512) * 8); \
    } while (0)

    f32x4 acc[8][4] = {};

    STAGE(0, 0);
    asm volatile("s_waitcnt vmcnt(0)" ::: "memory");
    __builtin_amdgcn_s_barrier();

    int cur = 0;
    for (int kt = 0; kt < K; kt += 32) {
        if (kt + 32 < K) STAGE(cur ^ 1, kt + 32);
        const unsigned short* la = &lds[cur][0];
        const unsigned short* lb = &lds[cur][8192];
        bf16x8 a[8], b[4];
        #pragma unroll
        for (int f = 0; f < 8; ++f)
            a[f] = *(const bf16x8*)(la + (wr * 64 + f * 8 + rh) * 64 + sl * 8);
        #pragma unroll
        for (int g = 0; g < 4; ++g)
            b[g] = *(const bf16x8*)(lb + (wc * 32 + g * 8 + rh) * 64 + sl * 8);
        __builtin_amdgcn_s_setprio(1);
        #pragma unroll
        for (int f = 0; f < 8; ++f)
            #pragma unroll
            for (int g = 0; g < 4; ++g)
                acc[f][g] = __builtin_amdgcn_mfma_f32_16x16x32_bf16(a[f], b[g], acc[f][g], 0, 0, 0);
        __builtin_amdgcn_s_setprio(0);
        asm volatile("s_waitcnt vmcnt(0)" ::: "memory");
        __builtin_amdgcn_s_barrier();
        cur ^= 1;
    }
#undef STAGE

    // C/D layout: col(n)=lane&15, row(m)=(lane>>4)*4+j  [m89 verified]
    if (MODE == 0) {
        // two 128-col chunks: restage to LDS (swizzled 8B granules), store hT col-major
        unsigned short* sm = &lds[0][0];   // 32768 ushorts = 64KB
        unsigned short* hT = (unsigned short*)Cout;
        #pragma unroll
        for (int ch = 0; ch < 2; ++ch) {
            if (ch) __syncthreads();
            if ((wc >> 1) == ch) {
                int wcL = wc & 1;
                #pragma unroll
                for (int fn = 0; fn < 4; ++fn) {
                    int lcol = wcL * 64 + fn * 16 + lr;
                    int gcol = n0 + ch * 128 + lcol;
                    float bv = (gcol < validN) ? bias[gcol] : 0.f;
                    #pragma unroll
                    for (int fm = 0; fm < 8; ++fm) {
                        int g = wr * 32 + fm * 4 + lh;   // 8B granule index (row/4)
                        ushort4 v4;
                        v4.x = f2bf(acc[fm][fn][0] + bv);
                        v4.y = f2bf(acc[fm][fn][1] + bv);
                        v4.z = f2bf(acc[fm][fn][2] + bv);
                        v4.w = f2bf(acc[fm][fn][3] + bv);
                        *(ushort4*)(sm + lcol * 256 + ((g ^ (lcol & 7)) << 2)) = v4;
                    }
                }
            }
            __syncthreads();
            int colLoc = t >> 2, q = t & 3;
            int gcol = n0 + ch * 128 + colLoc;
            if (gcol < validN) {
                #pragma unroll
                for (int i = 0; i < 16; ++i) {
                    int g = q * 16 + i;
                    ushort4 v4 = *(const ushort4*)(sm + colLoc * 256 + ((g ^ (colLoc & 7)) << 2));
                    *(ushort4*)&hT[(size_t)gcol * MPAD + m0 + g * 4] = v4;
                }
            }
        }
    } else {
        float* out = (float*)Cout;
        #pragma unroll
        for (int fm = 0; fm < 8; ++fm) {
            #pragma unroll
            for (int fn = 0; fn < 4; ++fn) {
                int gcol = n0 + wc * 64 + fn * 16 + lr;
                float bv = bias[gcol];
                #pragma unroll
                for (int j = 0; j < 4; ++j) {
                    int grow = m0 + wr * 128 + fm * 16 + lh * 4 + j;
                    if (grow < validM)
                        out[(size_t)grow * D_MODEL + gcol] = acc[fm][fn][j] + bv;
                }
            }
        }
    }
}

// ---- fold + normalize + relu -> per-(b2,c) padded image (bf16) ----
// grid (HP, 800), block 128: y = blockIdx.x, x = threadIdx.x. Reads hT coalesced.
__global__ void fold_norm(const unsigned short* __restrict__ hT, unsigned short* __restrict__ img2) {
    int y  = blockIdx.x;
    int bc = blockIdx.y;              // b2*40 + c
    int x  = threadIdx.x;
    if (x >= WP) return;
    int b2 = bc / 40, c = bc % 40;
    float val = 0.f;
    if (y >= 3 && y < 63 && x >= 3 && x < 111) {
        int kiA[3], biA[3], nki = 0;
        for (int ki = y % 3; ki < 7; ki += 3) {
            int bi = (y - ki) / 3;
            if (y - ki >= 0 && bi < 20) { kiA[nki] = ki; biA[nki] = bi; ++nki; }
        }
        int kjA[3], bjA[3], nkj = 0;
        for (int kj = x % 3; kj < 7; kj += 3) {
            int bj = (x - kj) / 3;
            if (x - kj >= 0 && bj < 36) { kjA[nkj] = kj; bjA[nkj] = bj; ++nkj; }
        }
        float s = 0.f;
        for (int i = 0; i < nki; ++i) {
            const unsigned short* base =
                hT + (size_t)(c * 49 + kiA[i] * 7) * MPAD + b2 * NVECS + biA[i] * 36;
            for (int j = 0; j < nkj; ++j)
                s += bf2f(base[kjA[j] * MPAD + bjA[j]]);
        }
        val = fmaxf(s / (float)(nki * nkj), 0.f);
    }
    img2[(size_t)bc * IMGPIX + y * WP + x] = f2bf(val);
}

// ---- unfold: h2b[row][hd] = img2[b2,c, (bi*3+ki), (bj*3+kj)]; zero pads ----
__global__ void unfold_k(const unsigned short* __restrict__ img2, unsigned short* __restrict__ h2b) {
    int row = blockIdx.x;             // 0..MPAD-1
    if (row >= MROWS) {
        for (int hd = threadIdx.x; hd < NPAD; hd += 256)
            h2b[(size_t)row * NPAD + hd] = 0;
        return;
    }
    int b2 = row / NVECS, v = row % NVECS;
    int bi = v / 36, bj = v % 36;
    for (int hd = threadIdx.x; hd < NPAD; hd += 256) {
        unsigned short val = 0;
        if (hd < HD) {
            int c = hd / 49, kk = hd % 49;
            int ki = kk / 7, kj = kk % 7;
            val = img2[(size_t)(b2 * 40 + c) * IMGPIX + (bi * 3 + ki) * WP + (bj * 3 + kj)];
        }
        h2b[(size_t)row * NPAD + hd] = val;
    }
}

extern "C" void kernel_launch(void* const* d_in, const int* in_sizes, int n_in,
                              void* d_out, int out_size, void* d_ws, size_t ws_size,
                              hipStream_t stream) {
    const float* x  = (const float*)d_in[0];
    const float* W1 = (const float*)d_in[1];
    const float* b1 = (const float*)d_in[2];
    const float* W2 = (const float*)d_in[3];
    const float* b2 = (const float*)d_in[4];
    float* out = (float*)d_out;

    // workspace layout (bf16 elements), total ~150.7 MB
    unsigned short* xb   = (unsigned short*)d_ws;                 // MPAD*512
    unsigned short* W1T  = xb   + (size_t)MPAD * D_MODEL;         // 2048*512
    unsigned short* W2T  = W1T  + (size_t)NPAD * D_MODEL;         // 512*2048
    unsigned short* hT   = W2T  + (size_t)D_MODEL * NPAD;         // NPAD*MPAD (transposed)
    unsigned short* h2b  = hT   + (size_t)NPAD * MPAD;            // MPAD*NPAD
    unsigned short* img2 = h2b  + (size_t)MPAD * NPAD;            // 800*7524

    cvt_x<<<(MPAD * D_MODEL / 4 + 255) / 256, 256, 0, stream>>>(x, xb);

    dim3 tb(32, 8);
    transpose_cvt<<<dim3(512 / 32, NPAD / 32), tb, 0, stream>>>(W1, W1T, D_MODEL, HD, NPAD, D_MODEL);
    transpose_cvt<<<dim3(NPAD / 32, 512 / 32), tb, 0, stream>>>(W2, W2T, HD, D_MODEL, D_MODEL, NPAD);

    // GEMM1: hT = (xb @ W1T^T + b1)^T   (bf16, transposed out)
    gemm_bt2<0><<<dim3(NPAD / 256, MPAD / 256), 512, 0, stream>>>(
        xb, W1T, b1, hT, D_MODEL, HD, MPAD);

    fold_norm<<<dim3(HP, 800), 128, 0, stream>>>(hT, img2);
    unfold_k<<<MPAD, 256, 0, stream>>>(img2, h2b);

    // GEMM2: out = h2b @ W2T^T + b2  (fp32, rows<14400 only)
    gemm_bt2<1><<<dim3(D_MODEL / 256, MPAD / 256), 512, 0, stream>>>(
        h2b, W2T, b2, out, NPAD, D_MODEL, MROWS);
}